// Round 1
// baseline (167.793 us; speedup 1.0000x reference)
//
#include <hip/hip_runtime.h>
#include <float.h>

#define H 64
#define W 512
#define SPLIT 8   // blocks per (tensor,h): 2*64*8 = 1024 blocks, 32 row-PAIRS each

// ---------------------------------------------------------------------------
// Fused masked-exp-norm row statistics for BOTH cost volumes, triangle-aware.
// R7 change: complementary row-pairing for perfect load balance + 2x ILP.
//   For tril, row i needs prefix (i+1) cols, row 511-i needs prefix (512-i):
//   together exactly 513 cols -> every pair (i, 511-i) costs exactly 3
//   wave-wide float4 half-chunks (short row: 1, long row: 2), for ANY i.
//   Mirrored identity holds for triu (suffixes). So:
//     - every block/wave has identical cost (kills the 57%-occupancy tail the
//       old FULLROW/halfrow block specialization caused),
//     - each iteration carries TWO independent rows -> two argmax butterflies,
//       two exp phases, two sum butterflies interleaved = 2x ILP in the
//       latency-bound shfl chains (VALUBusy was 35%).
//   Bytes touched are unchanged vs the old coarse-triangle scheme.
// Per row i, without materializing att:
//   disp_ini[i] = i - sum_j att[i,j]*j
//   colsum[j]  += sum_i att[i,j]     (LDS -> global atomics, cs pre-zeroed)
//   raw[i]      = 3-tap subpixel: t1 = pscale*(i*t0-w0) [tril] /
//                                      pscale*(w0-i*t0) [triu]
// lower (cost2/tril, valid j<=i) -> disp_r2l, cs_r2l, out ch2
// upper (cost1/triu, valid j>=i) -> disp_l2r, cs_l2r, out ch3
// Masked elements -> -FLT_MAX so exp()->0; masked zeros join the row max
// whenever the row has any masked element; argmax = first occurrence.
// ---------------------------------------------------------------------------
template<bool LOWER>
__device__ __forceinline__ void process_pairs(
    const float* __restrict__ hb, const int h, const int s,
    const int lane, const int wid,
    float* __restrict__ disp, float* __restrict__ raw, float* scol)
{
  const float pscale = 2.0f / 511.0f;   // linspace(0,2,512) step

  // column maps: chunk0 = cols [0,256), chunk1 = cols [256,512)
  int   j0i[4], j1i[4];
  float jf0[4], jf1[4];
  #pragma unroll
  for (int k = 0; k < 4; k++) {
    j0i[k] = lane * 4 + k;
    j1i[k] = 256 + lane * 4 + k;
    jf0[k] = (float)j0i[k];
    jf1[k] = (float)j1i[k];
  }

  float cacc[8];
  #pragma unroll
  for (int q = 0; q < 8; q++) cacc[q] = 0.f;

  for (int t = wid; t < 32; t += 8) {
    const int i  = s * 32 + t;               // short-side pair index, in [0,256)
    // short row touches ONE half-chunk, long row touches both:
    //   LOWER: short = i      (prefix i+1 <= 256 cols, chunk0)
    //          long  = 511-i  (prefix >= 257 cols: chunk0 full + chunk1 masked)
    //   UPPER: short = 511-i  (suffix <= 256 cols, chunk1)
    //          long  = i      (suffix >= 257 cols: chunk0 masked + chunk1 full)
    const int iS = LOWER ? i : (W - 1 - i);
    const int iL = LOWER ? (W - 1 - i) : i;
    const float* rpS = hb + (size_t)iS * W;
    const float* rpL = hb + (size_t)iL * W;

    float cS[4], cL[8];
    {
      const float4 vS = ((const float4*)rpS)[(LOWER ? 0 : 64) + lane];
      cS[0]=vS.x; cS[1]=vS.y; cS[2]=vS.z; cS[3]=vS.w;
      const float4 v0 = ((const float4*)rpL)[lane];
      cL[0]=v0.x; cL[1]=v0.y; cL[2]=v0.z; cL[3]=v0.w;
      const float4 v1 = ((const float4*)rpL)[64 + lane];
      cL[4]=v1.x; cL[5]=v1.y; cL[6]=v1.z; cL[7]=v1.w;
    }

    // ---- phase 1: mask (triangle) + max + argmax (first occurrence)
    float bS = -FLT_MAX; int jS = 1024;
    #pragma unroll
    for (int k = 0; k < 4; k++) {
      const int j = LOWER ? j0i[k] : j1i[k];
      const bool vld = LOWER ? (j <= iS) : (j >= iS);
      const float v = vld ? cS[k] : -FLT_MAX;
      cS[k] = v;
      if (v > bS) { bS = v; jS = j; }          // j ascending in k
    }
    float bL = -FLT_MAX; int jL = 1024;
    #pragma unroll
    for (int k = 0; k < 8; k++) {
      const int j = (k < 4) ? j0i[k] : j1i[k - 4];
      // which chunk of the long row carries the diagonal (compile-time per k)
      const bool NM = LOWER ? (k >= 4) : (k < 4);
      float v = cL[k];
      if (NM) {
        const bool vld = LOWER ? (j <= iL) : (j >= iL);
        v = vld ? v : -FLT_MAX;
        cL[k] = v;
      }
      if (v > bL) { bL = v; jL = j; }          // j ascending in k
    }
    #pragma unroll
    for (int off = 32; off; off >>= 1) {       // two interleaved butterflies
      const float ovS = __shfl_xor(bS, off);
      const int   ojS = __shfl_xor(jS, off);
      if (ovS > bS || (ovS == bS && ojS < jS)) { bS = ovS; jS = ojS; }
      const float ovL = __shfl_xor(bL, off);
      const int   ojL = __shfl_xor(jL, off);
      if (ovL > bL || (ovL == bL && ojL < jL)) { bL = ovL; jL = ojL; }
    }

    // ---- issue tap reloads early (wave-uniform, L2-hot; overlap exp phase)
    const int jSm = jS - 1, jSp = jS + 1;
    const int jLm = jL - 1, jLp = jL + 1;
    const float cmS = rpS[min(max(jSm, 0), W - 1)];
    const float cpS = rpS[min(jSp, W - 1)];
    const float cmL = rpL[min(max(jLm, 0), W - 1)];
    const float cpL = rpL[min(jLp, W - 1)];

    // short row ALWAYS has masked elements (iS<=255 for tril / iS>=256 for
    // triu); long row has none only at the full row (i==0) -> zeros join max
    const float mxS = fmaxf(bS, 0.f);
    const float mxL = (i > 0) ? fmaxf(bL, 0.f) : bL;

    // ---- phase 2: exp + sums (c[] overwritten with e; masked -> 0)
    float sS = 0.f, wS = 0.f;
    #pragma unroll
    for (int k = 0; k < 4; k++) {
      const float e = __expf(cS[k] - mxS);
      cS[k] = e;
      sS += e;
      wS = fmaf(e, LOWER ? jf0[k] : jf1[k], wS);
    }
    float sL = 0.f, wL = 0.f;
    #pragma unroll
    for (int k = 0; k < 8; k++) {
      const float e = __expf(cL[k] - mxL);
      cL[k] = e;
      sL += e;
      wL = fmaf(e, (k < 4) ? jf0[k] : jf1[k - 4], wL);
    }
    #pragma unroll
    for (int off = 32; off; off >>= 1) {       // two interleaved sum butterflies
      sS += __shfl_xor(sS, off);
      wS += __shfl_xor(wS, off);
      sL += __shfl_xor(sL, off);
      wL += __shfl_xor(wL, off);
    }
    const float invS = 1.f / (sS + 1e-8f);
    const float invL = 1.f / (sL + 1e-8f);

    #pragma unroll
    for (int k = 0; k < 4; k++) {
      const int qS = LOWER ? k : 4 + k;        // short row's half
      cacc[qS]    = fmaf(cS[k],     invS, cacc[qS]);
      cacc[k]     = fmaf(cL[k],     invL, cacc[k]);
      cacc[4 + k] = fmaf(cL[4 + k], invL, cacc[4 + k]);
    }

    if (lane == 0) {
      #pragma unroll
      for (int rr = 0; rr < 2; rr++) {
        const int   ii   = rr ? iL : iS;
        const float bb   = rr ? bL : bS;
        const int   bj   = rr ? jL : jS;
        const float mx   = rr ? mxL : mxS;
        const float inv  = rr ? invL : invS;
        const float wsum = rr ? wL : wS;
        const float cm_  = rr ? cmL : cmS;
        const float cp_  = rr ? cpL : cpS;
        const int bjm = bj - 1, bjp = bj + 1;
        // 3-tap subpixel: validity per reference zero-padded triangle gather
        const bool pv = LOWER ? (bjm >= 0)  : (bjm >= ii);
        const bool nv = LOWER ? (bjp <= ii) : (bjp <= W - 1);
        const float e_h = __expf(bb - mx);
        const float e_p = pv ? __expf(cm_ - mx) : 0.f;
        const float e_n = nv ? __expf(cp_ - mx) : 0.f;
        const float t0 = e_p + e_h + e_n;
        const float w0 = fmaf(e_p, (float)bjm, fmaf(e_h, (float)bj, e_n * (float)bjp));
        const float fi = (float)ii;
        disp[h * W + ii] = fi - wsum * inv;
        const float n0 = t0 * inv;             // sum of the 3 att taps
        const float t1 = pscale * (LOWER ? (fi * t0 - w0) : (w0 - fi * t0));
        raw[h * W + ii] = (t1 * inv) / (n0 < 0.1f ? 1.f : n0);
      }
    }
  }

  // colsum partials: regs -> LDS atomics (8-wave combine)
  #pragma unroll
  for (int q = 0; q < 4; q++) atomicAdd(&scol[j0i[q]], cacc[q]);
  #pragma unroll
  for (int q = 0; q < 4; q++) atomicAdd(&scol[j1i[q]], cacc[4 + q]);
}

__global__ __launch_bounds__(512) void attn_stats_all(
    const float* __restrict__ cost1, const float* __restrict__ cost2,
    float* __restrict__ disp_r2l, float* __restrict__ disp_l2r,
    float* __restrict__ cs_r2l,  float* __restrict__ cs_l2r,
    float* __restrict__ out)
{
  __shared__ float scol[W];
  const int tid  = threadIdx.x;
  const int lane = tid & 63;
  const int wid  = tid >> 6;              // 0..7
  const int gid  = blockIdx.x;
  const bool lower = (gid & 1) == 0;      // interleave tensors across CUs/XCDs
  const int rest = gid >> 1;
  const int h    = rest >> 3;
  const int s    = rest & 7;              // pair block: pairs [s*32, s*32+32)

  const float* cost = lower ? cost2 : cost1;
  float* disp = lower ? disp_r2l : disp_l2r;
  float* csum = lower ? cs_r2l  : cs_l2r;
  float* raw  = out + (lower ? 2 : 3) * (H * W);
  const float* hb = cost + (size_t)h * W * W;

  scol[tid] = 0.f;
  __syncthreads();

  if (lower) process_pairs<true >(hb, h, s, lane, wid, disp, raw, scol);
  else       process_pairs<false>(hb, h, s, lane, wid, disp, raw, scol);

  __syncthreads();
  // every block touches both halves now (long rows span chunk0+chunk1)
  atomicAdd(&csum[h * W + tid], scol[tid]);
}

// ---------------------------------------------------------------------------
// Closed-form hole fill (the W-step scan converges to this):
//   valid i            -> disp_ini[i]
//   invalid, valid p<i -> disp_ini[p] * (1+1e-4)^-(i-p)   (left-to-right pass)
//   invalid prefix     -> disp_ini[p0] * (1+1e-4)^-(p0-i) (right-to-left pass)
//   no valid in row    -> 0
// One wave per (pair, h) row.
// ---------------------------------------------------------------------------
__global__ __launch_bounds__(64) void fill_rows(
    const float* __restrict__ dispA, const float* __restrict__ csA,
    const float* __restrict__ dispB, const float* __restrict__ csB,
    float* __restrict__ out)
{
  __shared__ float xrow[W];
  const int pair = blockIdx.x >> 6;   // 0: ch0 (r2l disp, vm_left), 1: ch1
  const int h    = blockIdx.x & 63;
  const float* dsp = (pair ? dispB : dispA) + h * W;
  const float* cs  = (pair ? csB  : csA ) + h * W;
  float* o = out + pair * (H * W) + h * W;
  const int lane = threadIdx.x;
  const int j0 = lane * 8;

  float x[8];
  bool m[8];
  int incl[8];
  int run = -1, fv = W;
  #pragma unroll
  for (int k = 0; k < 8; k++) {
    x[k] = dsp[j0 + k];
    m[k] = cs[j0 + k] > 0.1f;
    xrow[j0 + k] = x[k];
    if (m[k]) { run = j0 + k; if (fv == W) fv = j0 + k; }
    incl[k] = run;
  }
  // inclusive max-scan across lanes of "last valid index in my segment"
  int v = run;
  #pragma unroll
  for (int off = 1; off < 64; off <<= 1) {
    const int tv = __shfl_up(v, off);
    if (lane >= off) v = max(v, tv);
  }
  int excl = __shfl_up(v, 1);
  if (lane == 0) excl = -1;
  // first valid index in the whole row
  int p0 = fv;
  #pragma unroll
  for (int off = 32; off; off >>= 1) p0 = min(p0, __shfl_xor(p0, off));
  __syncthreads();

  const float C2 = -1.4426229e-4f;  // -log2(1 + 1e-4)
  #pragma unroll
  for (int k = 0; k < 8; k++) {
    const int jj = j0 + k;
    float ov;
    if (m[k]) {
      ov = x[k];
    } else {
      const int p = max(excl, incl[k]);
      if (p >= 0)        ov = xrow[p]  * exp2f(C2 * (float)(jj - p));
      else if (p0 < W)   ov = xrow[p0] * exp2f(C2 * (float)(p0 - jj));
      else               ov = 0.f;
    }
    o[jj] = ov;
  }
}

extern "C" void kernel_launch(void* const* d_in, const int* in_sizes, int n_in,
                              void* d_out, int out_size, void* d_ws, size_t ws_size,
                              hipStream_t stream) {
  const float* cost1 = (const float*)d_in[0];  // -> att_l2r (triu)
  const float* cost2 = (const float*)d_in[1];  // -> att_r2l (tril)
  float* out = (float*)d_out;                  // [4, H, W]
  float* w = (float*)d_ws;
  float* disp_r2l_ini = w;                     // 32768 floats (from cost2)
  float* disp_l2r_ini = w + 32768;             // (from cost1)
  float* cs_l2r       = w + 65536;             // colsums of att_l2r -> vm_left
  float* cs_r2l       = w + 98304;             // colsums of att_r2l -> vm_right

  hipMemsetAsync(cs_l2r, 0, 2 * (size_t)H * W * sizeof(float), stream);

  attn_stats_all<<<2 * H * SPLIT, 512, 0, stream>>>(
      cost1, cost2, disp_r2l_ini, disp_l2r_ini, cs_r2l, cs_l2r, out);

  // ch0 = regress(att_r2l, vm_left); ch1 = regress(att_l2r, vm_right)
  fill_rows<<<2 * H, 64, 0, stream>>>(disp_r2l_ini, cs_l2r,
                                      disp_l2r_ini, cs_r2l, out);
}